// Round 13
// baseline (800.216 us; speedup 1.0000x reference)
//
#include <hip/hip_runtime.h>

#define DZ 64
#define DX 32
#define DS 16
#define TT 1024
#define NS 1024
#define SNZ (NS * DZ)
#define SNX (NS * DX)
#define SU  (NS * DS)

// LDS overlay (floats). ALL weight staging passes through this same region
// in chunks, so every weight's LDS source address is clobbered every step
// -> re-reads are unsound -> weights must stay register-resident.
#define ZR_O 0                 // raw z_t       [64]
#define RZ_O 64                // relu z_t      [64]
#define PM_O 128               // mu partials   [par2][wv4][64]
#define PX_O 640               // x  partials   [par2][wv4][32]
#define SMEM_FLOATS 896        // 3.6 KB -> LDS never caps occupancy

__device__ __forceinline__ float softplus_eps(float x) {
    // jax.nn.softplus = max(x,0) + log1p(exp(-|x|)); +1e-6
    return fmaxf(x, 0.f) + log1pf(expf(-fabsf(x))) + 1e-6f;
}

// 4 waves per sim (k-quarters), 1024 blocks x 256 threads = 4096 waves
// -> 4 waves/SIMD. One __syncthreads per step; partials parity-buffered;
// all 4 waves recompute z' bit-identically (fixed combine order).
__global__ __launch_bounds__(256, 4) void plrnn_q_kernel(
    const float* __restrict__ u,   // (T, N, 16)
    const float* __restrict__ z0,  // (N, 64)
    const float* __restrict__ nz,  // (T, N, 64)
    const float* __restrict__ nx,  // (T, N, 32)
    const float* __restrict__ AW,  // (64, 64)
    const float* __restrict__ Cm,  // (64, 16)
    const float* __restrict__ Bm,  // (32, 64)
    const float* __restrict__ Q,   // (64,)
    const float* __restrict__ R,   // (32,)
    float* __restrict__ zo,        // (T, N, 64)
    float* __restrict__ xo)        // (T, N, 32)
{
    const int tid  = threadIdx.x;
    const int lane = tid & 63;
    const int wvu  = __builtin_amdgcn_readfirstlane(tid >> 6);  // k-quarter 0..3
    const int p    = lane & 31;
    const int h    = lane >> 5;
    const int kx   = 16 * wvu + 8 * h;      // this lane's 8-k slice for x
    const int sim  = __builtin_amdgcn_readfirstlane((int)blockIdx.x);

    __shared__ float smem[SMEM_FLOATS];

    // ---- chunked staging through the overlay region ----
    float Wrow[16];
    float Ad = 0.f;
    for (int ch = 0; ch < 8; ++ch) {        // AW: 8 chunks of 8 rows (pad 65)
        __syncthreads();
        for (int i = tid; i < 520; i += 256) {
            const int rr = i / 65, cc = i - rr * 65;
            if (cc < 64) smem[i] = AW[(ch * 8 + rr) * 64 + cc];
        }
        __syncthreads();
        if ((lane >> 3) == ch) {
            const int r = lane & 7;
            #pragma unroll
            for (int j2 = 0; j2 < 16; ++j2) {
                const int k = 16 * wvu + j2;
                const float w = smem[r * 65 + k];
                Wrow[j2] = (k == lane) ? 0.f : w;   // zero diagonal
            }
            Ad = smem[r * 65 + lane];               // diagonal element
        }
    }
    float Crow[4];
    for (int ch = 0; ch < 2; ++ch) {        // C: 2 chunks of 32 rows (pad 17)
        __syncthreads();
        for (int i = tid; i < 544; i += 256) {
            const int rr = i / 17, cc = i - rr * 17;
            if (cc < 16) smem[i] = Cm[(ch * 32 + rr) * 16 + cc];
        }
        __syncthreads();
        if ((lane >> 5) == ch) {
            const int r = lane & 31;
            #pragma unroll
            for (int j2 = 0; j2 < 4; ++j2) Crow[j2] = smem[r * 17 + 4 * wvu + j2];
        }
    }
    float Brow[8];
    for (int ch = 0; ch < 4; ++ch) {        // B: 4 chunks of 8 rows (pad 65)
        __syncthreads();
        for (int i = tid; i < 520; i += 256) {
            const int rr = i / 65, cc = i - rr * 65;
            if (cc < 64) smem[i] = Bm[(ch * 8 + rr) * 64 + cc];
        }
        __syncthreads();
        if ((p >> 3) == ch) {
            const int r = p & 7;
            #pragma unroll
            for (int j2 = 0; j2 < 8; ++j2) Brow[j2] = smem[r * 65 + kx + j2];
        }
    }

    const float qv = softplus_eps(Q[lane]);
    const float rv = softplus_eps(R[p]);

    __syncthreads();   // staging reads done before overlay is clobbered

    float zl = z0[sim * DZ + lane];         // identical copy in all 4 waves

    const float* nzb = nz + sim * DZ;
    const float* nxb = nx + sim * DX;
    const float* ub  = u  + sim * DS + 4 * wvu;   // wave-uniform u slice
    float* zob = zo + sim * DZ;
    float* xob = xo + sim * DX;

    // prefetch depth 4, index-clamped (tail-safe)
    float nzp[4], nxp[4];
    float4 uqp[4];
    #pragma unroll
    for (int j = 0; j < 4; ++j) {
        nzp[j] = nzb[lane + j * SNZ];
        nxp[j] = nxb[p + j * SNX];
        uqp[j] = *(const float4*)(ub + j * SU);
    }

    for (int t0 = 0; t0 < TT; t0 += 4) {
        #pragma unroll
        for (int j = 0; j < 4; ++j) {
            const int t   = t0 + j;
            const int par = j & 1;
            const float  vnz = nzp[j];
            const float  vnx = nxp[j];
            const float4 uq  = uqp[j];

            // publish z_t (all waves write identical bits; reads are own-write)
            smem[ZR_O + lane] = zl;
            smem[RZ_O + lane] = fmaxf(zl, 0.f);
            if (wvu == 0) zob[lane + t * SNZ] = zl;   // emit z_t (pre-update)

            // u-dot: wave-uniform scalar float4 (no LDS, no per-lane loads)
            float m0 = Crow[0] * uq.x, m1 = Crow[1] * uq.y;
            float m2 = Crow[2] * uq.z, m3 = Crow[3] * uq.w;

            // refill prefetch (clamped; tail values loaded but unused)
            {
                int tn = t + 4; tn = (tn < TT) ? tn : (TT - 1);
                nzp[j] = nzb[lane + tn * SNZ];
                nxp[j] = nxb[p + tn * SNX];
                uqp[j] = *(const float4*)(ub + tn * SU);
            }

            // W-quarter dot: 4 broadcast ds_read_b128 of relu(z_t)
            #pragma unroll
            for (int k4 = 0; k4 < 4; ++k4) {
                const float4 zz = *(const float4*)&smem[RZ_O + 16 * wvu + 4 * k4];
                m0 = fmaf(Wrow[4 * k4 + 0], zz.x, m0);
                m1 = fmaf(Wrow[4 * k4 + 1], zz.y, m1);
                m2 = fmaf(Wrow[4 * k4 + 2], zz.z, m2);
                m3 = fmaf(Wrow[4 * k4 + 3], zz.w, m3);
            }

            // x 8-k slice dot of raw z_t (2 reads), halves merged by shfl
            float xa0, xa1;
            {
                const float4 za = *(const float4*)&smem[ZR_O + kx];
                const float4 zb = *(const float4*)&smem[ZR_O + kx + 4];
                xa0 = Brow[0] * za.x;            xa1 = Brow[1] * za.y;
                xa0 = fmaf(Brow[2], za.z, xa0);  xa1 = fmaf(Brow[3], za.w, xa1);
                xa0 = fmaf(Brow[4], zb.x, xa0);  xa1 = fmaf(Brow[5], zb.y, xa1);
                xa0 = fmaf(Brow[6], zb.z, xa0);  xa1 = fmaf(Brow[7], zb.w, xa1);
            }
            float xpart = xa0 + xa1;
            xpart += __shfl_xor(xpart, 32);      // merge the two 8-k halves

            smem[PM_O + par * 256 + wvu * 64 + lane] = (m0 + m1) + (m2 + m3);
            if (lane < 32) smem[PX_O + par * 128 + wvu * 32 + p] = xpart;

            __syncthreads();   // the ONE barrier per step

            // combine partials in FIXED order -> all waves' z' bit-identical
            const float q0 = smem[PM_O + par * 256 +   0 + lane];
            const float q1 = smem[PM_O + par * 256 +  64 + lane];
            const float q2 = smem[PM_O + par * 256 + 128 + lane];
            const float q3 = smem[PM_O + par * 256 + 192 + lane];

            if (wvu == 3 && lane < 32) {         // wave3 finishes + stores x_t
                const float xs = (smem[PX_O + par * 128 +  0 + p]
                                + smem[PX_O + par * 128 + 32 + p])
                               + (smem[PX_O + par * 128 + 64 + p]
                                + smem[PX_O + par * 128 + 96 + p]);
                xob[p + t * SNX] = fmaf(vnx, rv, xs);
            }

            // z_{t+1} = A_diag*z + (sum of 4 quarter-partials) + q*nz
            zl = fmaf(qv, vnz, fmaf(Ad, zl, (q0 + q1) + (q2 + q3)));
        }
    }
}

extern "C" void kernel_launch(void* const* d_in, const int* in_sizes, int n_in,
                              void* d_out, int out_size, void* d_ws, size_t ws_size,
                              hipStream_t stream) {
    const float* u_  = (const float*)d_in[0];
    const float* z0_ = (const float*)d_in[1];
    const float* nz_ = (const float*)d_in[2];
    const float* nx_ = (const float*)d_in[3];
    const float* AW_ = (const float*)d_in[4];
    const float* C_  = (const float*)d_in[5];
    const float* B_  = (const float*)d_in[6];
    const float* Q_  = (const float*)d_in[7];
    const float* R_  = (const float*)d_in[8];

    float* zo = (float*)d_out;                 // (T,N,64) first
    float* xo = zo + (size_t)TT * NS * DZ;     // then (T,N,32)

    hipLaunchKernelGGL(plrnn_q_kernel, dim3(NS), dim3(256), 0, stream,
                       u_, z0_, nz_, nx_, AW_, C_, B_, Q_, R_, zo, xo);
}

// Round 14
// 785.820 us; speedup vs baseline: 1.0183x; 1.0183x over previous
//
#include <hip/hip_runtime.h>

#define DZ 64
#define DX 32
#define DS 16
#define TT 1024
#define NS 1024
#define SNZ (NS * DZ)
#define SNX (NS * DX)
#define SU  (NS * DS)

// ---- LDS layout (floats) ----
// Monolithic staging (R12-proven residency pattern):
#define AW_B 0
#define C_B  (AW_B + DZ * (DZ + 1))      // 4160
#define B_B  (C_B + DZ * (DS + 1))       // 5248
#define SMEM_FLOATS (B_B + DX * (DZ + 1))   // 7328 floats = 29.3 KB
// runtime overlay ALIASES the AW staging region (anti-remat clobber):
#define ZR_O 0                 // raw z_t       [64]
#define RZ_O 64                // relu z_t      [64]
#define PM_O 128               // mu partials   [par2][wv4][64]
#define PX_O 640               // x  partials   [par2][wv4][32]  (ends at 895)

__device__ __forceinline__ float softplus_eps(float x) {
    // jax.nn.softplus = max(x,0) + log1p(exp(-|x|)); +1e-6
    return fmaxf(x, 0.f) + log1pf(expf(-fabsf(x))) + 1e-6f;
}

// 4 waves per sim (k-quarters), 1024 blocks x 256 threads = 4096 waves
// -> 4 waves/SIMD. One __syncthreads per step; partials parity-buffered;
// all 4 waves recompute z' bit-identically (fixed combine order).
// Staging is MONOLITHIC + unconditional unrolled reads (R13 lesson: chunked
// staging with guarded writes in a runtime loop demoted weights to scratch,
// VGPR_Count=40 -> 800us).
__global__ __launch_bounds__(256, 4) void plrnn_q_kernel(
    const float* __restrict__ u,   // (T, N, 16)
    const float* __restrict__ z0,  // (N, 64)
    const float* __restrict__ nz,  // (T, N, 64)
    const float* __restrict__ nx,  // (T, N, 32)
    const float* __restrict__ AW,  // (64, 64)
    const float* __restrict__ Cm,  // (64, 16)
    const float* __restrict__ Bm,  // (32, 64)
    const float* __restrict__ Q,   // (64,)
    const float* __restrict__ R,   // (32,)
    float* __restrict__ zo,        // (T, N, 64)
    float* __restrict__ xo)        // (T, N, 32)
{
    const int tid  = threadIdx.x;
    const int lane = tid & 63;
    const int wvu  = __builtin_amdgcn_readfirstlane(tid >> 6);  // k-quarter 0..3
    const int p    = lane & 31;
    const int h    = lane >> 5;
    const int kx   = 16 * wvu + 8 * h;      // this lane's 8-k slice for x
    const int sim  = __builtin_amdgcn_readfirstlane((int)blockIdx.x);

    __shared__ float smem[SMEM_FLOATS];

    {   // one-time monolithic stage (256 threads): AW 16/thr, C 4/thr, B 8/thr
        const int r = tid >> 2;
        const int c = (tid & 3) * 16;
        #pragma unroll
        for (int k = 0; k < 16; ++k) smem[AW_B + r * (DZ + 1) + c + k] = AW[r * DZ + c + k];
        const int cc = (tid & 3) * 4;
        #pragma unroll
        for (int k = 0; k < 4; ++k) smem[C_B + r * (DS + 1) + cc + k] = Cm[r * DS + cc + k];
        const int br = tid >> 3;
        const int bc = (tid & 7) * 8;
        #pragma unroll
        for (int k = 0; k < 8; ++k) smem[B_B + br * (DZ + 1) + bc + k] = Bm[br * DZ + bc + k];
    }
    __syncthreads();

    // per-lane weight slices -> registers: UNCONDITIONAL, compile-time indices
    float Wrow[16];                       // W_off[lane][16wvu .. 16wvu+15]
    #pragma unroll
    for (int j = 0; j < 16; ++j) {
        const int k = 16 * wvu + j;
        const float w = smem[AW_B + lane * (DZ + 1) + k];
        Wrow[j] = (k == lane) ? 0.f : w;  // zero diagonal (select, not index)
    }
    const float Ad = smem[AW_B + lane * (DZ + 1) + lane];   // diagonal
    float Crow[4];                        // C[lane][4wvu .. 4wvu+3]
    #pragma unroll
    for (int j = 0; j < 4; ++j) Crow[j] = smem[C_B + lane * (DS + 1) + 4 * wvu + j];
    float Brow[8];                        // B[p][kx .. kx+7]
    #pragma unroll
    for (int j = 0; j < 8; ++j) Brow[j] = smem[B_B + p * (DZ + 1) + kx + j];

    const float qv = softplus_eps(Q[lane]);
    const float rv = softplus_eps(R[p]);

    __syncthreads();   // staging reads done before overlay clobbers AW region

    float zl = z0[sim * DZ + lane];       // identical copy in all 4 waves

    const float* nzb = nz + sim * DZ;
    const float* nxb = nx + sim * DX;
    const float* ub  = u  + sim * DS + 4 * wvu;   // wave-uniform u slice
    float* zob = zo + sim * DZ;
    float* xob = xo + sim * DX;

    // prefetch depth 4, index-clamped (tail-safe)
    float nzp[4], nxp[4];
    float4 uqp[4];
    #pragma unroll
    for (int j = 0; j < 4; ++j) {
        nzp[j] = nzb[lane + j * SNZ];
        nxp[j] = nxb[p + j * SNX];
        uqp[j] = *(const float4*)(ub + j * SU);
    }

    for (int t0 = 0; t0 < TT; t0 += 4) {
        #pragma unroll
        for (int j = 0; j < 4; ++j) {
            const int t   = t0 + j;
            const int par = j & 1;
            const float  vnz = nzp[j];
            const float  vnx = nxp[j];
            const float4 uq  = uqp[j];

            // publish z_t (all waves write identical bits)
            smem[ZR_O + lane] = zl;
            smem[RZ_O + lane] = fmaxf(zl, 0.f);
            if (wvu == 0) zob[lane + t * SNZ] = zl;   // emit z_t (pre-update)

            // u-dot: wave-uniform float4 (no LDS, no per-lane loads)
            float m0 = Crow[0] * uq.x, m1 = Crow[1] * uq.y;
            float m2 = Crow[2] * uq.z, m3 = Crow[3] * uq.w;

            // refill prefetch (clamped; tail values loaded but unused)
            {
                int tn = t + 4; tn = (tn < TT) ? tn : (TT - 1);
                nzp[j] = nzb[lane + tn * SNZ];
                nxp[j] = nxb[p + tn * SNX];
                uqp[j] = *(const float4*)(ub + tn * SU);
            }

            // W-quarter dot: 4 broadcast ds_read_b128 of relu(z_t)
            #pragma unroll
            for (int k4 = 0; k4 < 4; ++k4) {
                const float4 zz = *(const float4*)&smem[RZ_O + 16 * wvu + 4 * k4];
                m0 = fmaf(Wrow[4 * k4 + 0], zz.x, m0);
                m1 = fmaf(Wrow[4 * k4 + 1], zz.y, m1);
                m2 = fmaf(Wrow[4 * k4 + 2], zz.z, m2);
                m3 = fmaf(Wrow[4 * k4 + 3], zz.w, m3);
            }

            // x 8-k slice dot of raw z_t (2 reads), halves merged by shfl
            float xa0, xa1;
            {
                const float4 za = *(const float4*)&smem[ZR_O + kx];
                const float4 zb = *(const float4*)&smem[ZR_O + kx + 4];
                xa0 = Brow[0] * za.x;            xa1 = Brow[1] * za.y;
                xa0 = fmaf(Brow[2], za.z, xa0);  xa1 = fmaf(Brow[3], za.w, xa1);
                xa0 = fmaf(Brow[4], zb.x, xa0);  xa1 = fmaf(Brow[5], zb.y, xa1);
                xa0 = fmaf(Brow[6], zb.z, xa0);  xa1 = fmaf(Brow[7], zb.w, xa1);
            }
            float xpart = xa0 + xa1;
            xpart += __shfl_xor(xpart, 32);      // merge the two 8-k halves

            smem[PM_O + par * 256 + wvu * 64 + lane] = (m0 + m1) + (m2 + m3);
            if (lane < 32) smem[PX_O + par * 128 + wvu * 32 + p] = xpart;

            __syncthreads();   // the ONE barrier per step

            // combine partials in FIXED order -> all waves' z' bit-identical
            const float q0 = smem[PM_O + par * 256 +   0 + lane];
            const float q1 = smem[PM_O + par * 256 +  64 + lane];
            const float q2 = smem[PM_O + par * 256 + 128 + lane];
            const float q3 = smem[PM_O + par * 256 + 192 + lane];

            if (wvu == 3 && lane < 32) {         // wave3 finishes + stores x_t
                const float xs = (smem[PX_O + par * 128 +  0 + p]
                                + smem[PX_O + par * 128 + 32 + p])
                               + (smem[PX_O + par * 128 + 64 + p]
                                + smem[PX_O + par * 128 + 96 + p]);
                xob[p + t * SNX] = fmaf(vnx, rv, xs);
            }

            // z_{t+1} = A_diag*z + (sum of 4 quarter-partials) + q*nz
            zl = fmaf(qv, vnz, fmaf(Ad, zl, (q0 + q1) + (q2 + q3)));
        }
    }
}

extern "C" void kernel_launch(void* const* d_in, const int* in_sizes, int n_in,
                              void* d_out, int out_size, void* d_ws, size_t ws_size,
                              hipStream_t stream) {
    const float* u_  = (const float*)d_in[0];
    const float* z0_ = (const float*)d_in[1];
    const float* nz_ = (const float*)d_in[2];
    const float* nx_ = (const float*)d_in[3];
    const float* AW_ = (const float*)d_in[4];
    const float* C_  = (const float*)d_in[5];
    const float* B_  = (const float*)d_in[6];
    const float* Q_  = (const float*)d_in[7];
    const float* R_  = (const float*)d_in[8];

    float* zo = (float*)d_out;                 // (T,N,64) first
    float* xo = zo + (size_t)TT * NS * DZ;     // then (T,N,32)

    hipLaunchKernelGGL(plrnn_q_kernel, dim3(NS), dim3(256), 0, stream,
                       u_, z0_, nz_, nx_, AW_, C_, B_, Q_, R_, zo, xo);
}

// Round 15
// 784.971 us; speedup vs baseline: 1.0194x; 1.0011x over previous
//
#include <hip/hip_runtime.h>

#define DZ 64
#define DX 32
#define DS 16
#define TT 1024
#define NS 1024
#define SNZ (NS * DZ)
#define SNX (NS * DX)
#define SU  (NS * DS)

// ---- LDS layout (floats) ----
// Monolithic staging (R12-proven residency pattern):
#define AW_B 0
#define C_B  (AW_B + DZ * (DZ + 1))      // 4160
#define B_B  (C_B + DZ * (DS + 1))       // 5248
#define SMEM_FLOATS (B_B + DX * (DZ + 1))   // 7328 floats = 29.3 KB
// runtime overlay ALIASES the AW staging region (anti-remat clobber):
#define ZR_O 0                 // raw z_t       [64]
#define RZ_O 64                // relu z_t      [64]
#define PM_O 128               // mu partials   [par2][wv4][64]
#define PX_O 640               // x  partials   [par2][wv4][32]  (ends at 895)

__device__ __forceinline__ float softplus_eps(float x) {
    // jax.nn.softplus = max(x,0) + log1p(exp(-|x|)); +1e-6
    return fmaxf(x, 0.f) + log1pf(expf(-fabsf(x))) + 1e-6f;
}

// 4 waves per sim (k-quarters), 1024 blocks x 256 threads = 4096 waves
// -> 4 waves/SIMD (if VGPR <= 128). One __syncthreads per step; partials
// parity-buffered; all 4 waves recompute z' bit-identically.
//
// __launch_bounds__(256, 2): R13/R14 lesson — declaring min-waves=4 caps
// the allocator at 128 VGPRs and flips it into aggressive-spill mode
// (VGPR_Count=40/44, weights evicted, 800us). min-waves=2 relaxes the cap
// to 256; expected allocation ~90-110 still gives 4 waves/SIMD in HW.
__global__ __launch_bounds__(256, 2) void plrnn_q_kernel(
    const float* __restrict__ u,   // (T, N, 16)
    const float* __restrict__ z0,  // (N, 64)
    const float* __restrict__ nz,  // (T, N, 64)
    const float* __restrict__ nx,  // (T, N, 32)
    const float* __restrict__ AW,  // (64, 64)
    const float* __restrict__ Cm,  // (64, 16)
    const float* __restrict__ Bm,  // (32, 64)
    const float* __restrict__ Q,   // (64,)
    const float* __restrict__ R,   // (32,)
    float* __restrict__ zo,        // (T, N, 64)
    float* __restrict__ xo)        // (T, N, 32)
{
    const int tid  = threadIdx.x;
    const int lane = tid & 63;
    const int wvu  = __builtin_amdgcn_readfirstlane(tid >> 6);  // k-quarter 0..3
    const int p    = lane & 31;
    const int h    = lane >> 5;
    const int kx   = 16 * wvu + 8 * h;      // this lane's 8-k slice for x
    const int sim  = __builtin_amdgcn_readfirstlane((int)blockIdx.x);

    __shared__ float smem[SMEM_FLOATS];

    {   // one-time monolithic stage (256 threads): AW 16/thr, C 4/thr, B 8/thr
        const int r = tid >> 2;
        const int c = (tid & 3) * 16;
        #pragma unroll
        for (int k = 0; k < 16; ++k) smem[AW_B + r * (DZ + 1) + c + k] = AW[r * DZ + c + k];
        const int cc = (tid & 3) * 4;
        #pragma unroll
        for (int k = 0; k < 4; ++k) smem[C_B + r * (DS + 1) + cc + k] = Cm[r * DS + cc + k];
        const int br = tid >> 3;
        const int bc = (tid & 7) * 8;
        #pragma unroll
        for (int k = 0; k < 8; ++k) smem[B_B + br * (DZ + 1) + bc + k] = Bm[br * DZ + bc + k];
    }
    __syncthreads();

    // per-lane weight slices -> registers: UNCONDITIONAL, compile-time indices
    float Wrow[16];                       // W_off[lane][16wvu .. 16wvu+15]
    #pragma unroll
    for (int j = 0; j < 16; ++j) {
        const int k = 16 * wvu + j;
        const float w = smem[AW_B + lane * (DZ + 1) + k];
        Wrow[j] = (k == lane) ? 0.f : w;  // zero diagonal (select, not index)
    }
    const float Ad = smem[AW_B + lane * (DZ + 1) + lane];   // diagonal
    float Crow[4];                        // C[lane][4wvu .. 4wvu+3]
    #pragma unroll
    for (int j = 0; j < 4; ++j) Crow[j] = smem[C_B + lane * (DS + 1) + 4 * wvu + j];
    float Brow[8];                        // B[p][kx .. kx+7]
    #pragma unroll
    for (int j = 0; j < 8; ++j) Brow[j] = smem[B_B + p * (DZ + 1) + kx + j];

    const float qv = softplus_eps(Q[lane]);
    const float rv = softplus_eps(R[p]);

    __syncthreads();   // staging reads done before overlay clobbers AW region

    float zl = z0[sim * DZ + lane];       // identical copy in all 4 waves

    const float* nzb = nz + sim * DZ;
    const float* nxb = nx + sim * DX;
    const float* ub  = u  + sim * DS + 4 * wvu;   // wave-uniform u slice
    float* zob = zo + sim * DZ;
    float* xob = xo + sim * DX;

    // prefetch depth 4, index-clamped (tail-safe)
    float nzp[4], nxp[4];
    float4 uqp[4];
    #pragma unroll
    for (int j = 0; j < 4; ++j) {
        nzp[j] = nzb[lane + j * SNZ];
        nxp[j] = nxb[p + j * SNX];
        uqp[j] = *(const float4*)(ub + j * SU);
    }

    for (int t0 = 0; t0 < TT; t0 += 4) {
        #pragma unroll
        for (int j = 0; j < 4; ++j) {
            const int t   = t0 + j;
            const int par = j & 1;
            const float  vnz = nzp[j];
            const float  vnx = nxp[j];
            const float4 uq  = uqp[j];

            // publish z_t (all waves write identical bits)
            smem[ZR_O + lane] = zl;
            smem[RZ_O + lane] = fmaxf(zl, 0.f);
            if (wvu == 0) zob[lane + t * SNZ] = zl;   // emit z_t (pre-update)

            // u-dot: wave-uniform float4 (no LDS, no per-lane loads)
            float m0 = Crow[0] * uq.x, m1 = Crow[1] * uq.y;
            float m2 = Crow[2] * uq.z, m3 = Crow[3] * uq.w;

            // refill prefetch (clamped; tail values loaded but unused)
            {
                int tn = t + 4; tn = (tn < TT) ? tn : (TT - 1);
                nzp[j] = nzb[lane + tn * SNZ];
                nxp[j] = nxb[p + tn * SNX];
                uqp[j] = *(const float4*)(ub + tn * SU);
            }

            // W-quarter dot: 4 broadcast ds_read_b128 of relu(z_t)
            #pragma unroll
            for (int k4 = 0; k4 < 4; ++k4) {
                const float4 zz = *(const float4*)&smem[RZ_O + 16 * wvu + 4 * k4];
                m0 = fmaf(Wrow[4 * k4 + 0], zz.x, m0);
                m1 = fmaf(Wrow[4 * k4 + 1], zz.y, m1);
                m2 = fmaf(Wrow[4 * k4 + 2], zz.z, m2);
                m3 = fmaf(Wrow[4 * k4 + 3], zz.w, m3);
            }

            // x 8-k slice dot of raw z_t (2 reads), halves merged by shfl
            float xa0, xa1;
            {
                const float4 za = *(const float4*)&smem[ZR_O + kx];
                const float4 zb = *(const float4*)&smem[ZR_O + kx + 4];
                xa0 = Brow[0] * za.x;            xa1 = Brow[1] * za.y;
                xa0 = fmaf(Brow[2], za.z, xa0);  xa1 = fmaf(Brow[3], za.w, xa1);
                xa0 = fmaf(Brow[4], zb.x, xa0);  xa1 = fmaf(Brow[5], zb.y, xa1);
                xa0 = fmaf(Brow[6], zb.z, xa0);  xa1 = fmaf(Brow[7], zb.w, xa1);
            }
            float xpart = xa0 + xa1;
            xpart += __shfl_xor(xpart, 32);      // merge the two 8-k halves

            smem[PM_O + par * 256 + wvu * 64 + lane] = (m0 + m1) + (m2 + m3);
            if (lane < 32) smem[PX_O + par * 128 + wvu * 32 + p] = xpart;

            __syncthreads();   // the ONE barrier per step

            // combine partials in FIXED order -> all waves' z' bit-identical
            const float q0 = smem[PM_O + par * 256 +   0 + lane];
            const float q1 = smem[PM_O + par * 256 +  64 + lane];
            const float q2 = smem[PM_O + par * 256 + 128 + lane];
            const float q3 = smem[PM_O + par * 256 + 192 + lane];

            if (wvu == 3 && lane < 32) {         // wave3 finishes + stores x_t
                const float xs = (smem[PX_O + par * 128 +  0 + p]
                                + smem[PX_O + par * 128 + 32 + p])
                               + (smem[PX_O + par * 128 + 64 + p]
                                + smem[PX_O + par * 128 + 96 + p]);
                xob[p + t * SNX] = fmaf(vnx, rv, xs);
            }

            // z_{t+1} = A_diag*z + (sum of 4 quarter-partials) + q*nz
            zl = fmaf(qv, vnz, fmaf(Ad, zl, (q0 + q1) + (q2 + q3)));
        }
    }
}

extern "C" void kernel_launch(void* const* d_in, const int* in_sizes, int n_in,
                              void* d_out, int out_size, void* d_ws, size_t ws_size,
                              hipStream_t stream) {
    const float* u_  = (const float*)d_in[0];
    const float* z0_ = (const float*)d_in[1];
    const float* nz_ = (const float*)d_in[2];
    const float* nx_ = (const float*)d_in[3];
    const float* AW_ = (const float*)d_in[4];
    const float* C_  = (const float*)d_in[5];
    const float* B_  = (const float*)d_in[6];
    const float* Q_  = (const float*)d_in[7];
    const float* R_  = (const float*)d_in[8];

    float* zo = (float*)d_out;                 // (T,N,64) first
    float* xo = zo + (size_t)TT * NS * DZ;     // then (T,N,32)

    hipLaunchKernelGGL(plrnn_q_kernel, dim3(NS), dim3(256), 0, stream,
                       u_, z0_, nz_, nx_, AW_, C_, B_, Q_, R_, zo, xo);
}

// Round 16
// 457.821 us; speedup vs baseline: 1.7479x; 1.7146x over previous
//
#include <hip/hip_runtime.h>

#define DZ 64
#define DX 32
#define DS 16
#define TT 1024
#define NS 1024
#define SNZ (NS * DZ)
#define SNX (NS * DX)
#define SU4 (NS * DS / 4)     // per-step stride in float4 units (u)

// ---- LDS layout (floats) ----
// staging (read once into registers):
#define AW_B 0
#define C_B  (AW_B + DZ * (DZ + 1))
#define B_B  (C_B + DZ * (DS + 1))
#define SMEM_FLOATS (B_B + DX * (DZ + 1))   // 7328 floats = 29.3 KB
// runtime overlay ALIASES the staging region (anti-remat clobber, R8-proven):
#define ZR_O 0                 // raw z_t      [64]
#define RZ_O DZ                // relu z_t     [64]
#define PM_O (2 * DZ)          // mu partials  [parity 2][kh 2][64]
#define PX_O (2 * DZ + 256)    // x partials   [parity 2][32] (wave0's half)

__device__ __forceinline__ float softplus_eps(float x) {
    // jax.nn.softplus = max(x,0) + log1p(exp(-|x|)); +1e-6
    return fmaxf(x, 0.f) + log1pf(expf(-fabsf(x))) + 1e-6f;
}

// Light barrier: order LDS (partials) across the block WITHOUT draining
// vmem. __syncthreads() emits s_waitcnt vmcnt(0) before s_barrier (m97),
// which serially drains the depth-4 prefetch loads issued mid-step ->
// ~550 stall cyc/step in R12. lgkmcnt(0) alone is enough for the LDS
// partials; prefetch loads stay in flight across the barrier and are
// consumed via compiler-inserted counted vmcnt at use, 4 steps later.
__device__ __forceinline__ void lds_barrier() {
    asm volatile("s_waitcnt lgkmcnt(0)" ::: "memory");
    __builtin_amdgcn_s_barrier();
}

// 2 waves per sim (k-halves), 1024 blocks x 128 threads = 2048 waves.
// R12 structure verbatim; only the in-loop barrier changed (R16).
__global__ __launch_bounds__(128, 2) void plrnn_split_kernel(
    const float* __restrict__ u,   // (T, N, 16)
    const float* __restrict__ z0,  // (N, 64)
    const float* __restrict__ nz,  // (T, N, 64)
    const float* __restrict__ nx,  // (T, N, 32)
    const float* __restrict__ AW,  // (64, 64)
    const float* __restrict__ Cm,  // (64, 16)
    const float* __restrict__ Bm,  // (32, 64)
    const float* __restrict__ Q,   // (64,)
    const float* __restrict__ R,   // (32,)
    float* __restrict__ zo,        // (T, N, 64)
    float* __restrict__ xo)        // (T, N, 32)
{
    const int tid  = threadIdx.x;
    const int lane = tid & 63;
    const int kh   = tid >> 6;            // k-half: 0 or 1 (wave id in block)
    const int p    = lane & 31;           // x output row
    const int sim  = __builtin_amdgcn_readfirstlane((int)blockIdx.x);

    __shared__ float smem[SMEM_FLOATS];

    {   // one-time stage (128 threads): AW 32/thr, C 8/thr, B 16/thr
        const int r = tid >> 1;
        const int c = (tid & 1) * 32;
        #pragma unroll
        for (int k = 0; k < 32; ++k) smem[AW_B + r * (DZ + 1) + c + k] = AW[r * DZ + c + k];
        const int cc = (tid & 1) * 8;
        #pragma unroll
        for (int k = 0; k < 8; ++k) smem[C_B + r * (DS + 1) + cc + k] = Cm[r * DS + cc + k];
        const int br = tid >> 2;
        const int bc = (tid & 3) * 16;
        #pragma unroll
        for (int k = 0; k < 16; ++k) smem[B_B + br * (DZ + 1) + bc + k] = Bm[br * DZ + bc + k];
    }
    __syncthreads();

    // per-lane weight slices -> registers (compile-time reg indices only)
    float Wrow[32];                       // W_off[lane][32kh .. 32kh+31]
    #pragma unroll
    for (int j = 0; j < 32; ++j) {
        const int k = 32 * kh + j;
        const float w = smem[AW_B + lane * (DZ + 1) + k];
        Wrow[j] = (k == lane) ? 0.f : w;  // zero diagonal (select, not reg-index)
    }
    const float Ad = smem[AW_B + lane * (DZ + 1) + lane];   // runtime LDS read: fine
    float Crow[8];                        // C[lane][8kh .. 8kh+7]
    #pragma unroll
    for (int j = 0; j < 8; ++j) Crow[j] = smem[C_B + lane * (DS + 1) + 8 * kh + j];
    const int kq = 32 * kh + ((lane >> 5) << 4);   // 16-k quarter for x
    float Brow[16];                       // B[p][kq .. kq+15]
    #pragma unroll
    for (int j = 0; j < 16; ++j) Brow[j] = smem[B_B + p * (DZ + 1) + kq + j];

    const float qv = softplus_eps(Q[lane]);
    const float rv = softplus_eps(R[p]);

    __syncthreads();   // staging reads done before runtime overlay clobbers it

    float zl = z0[sim * DZ + lane];       // both waves: identical copy of z_t

    // uniform bases (SGPR) + small int indices -> scalar-friendly addressing
    const float*  nzb = nz + sim * DZ;
    const float*  nxb = nx + sim * DX;
    const float4* ub4 = (const float4*)(u + sim * DS + 8 * kh);  // wave's 8 u's
    float* zob = zo + sim * DZ;
    float* xob = xo + sim * DX;

    // prefetch depth 4, index-clamped (R3-proven safe at the tail)
    float nzp[4], nxp[4];
    float4 upA[4], upB[4];
    #pragma unroll
    for (int j = 0; j < 4; ++j) {
        nzp[j] = nzb[lane + j * SNZ];
        nxp[j] = nxb[p + j * SNX];
        upA[j] = ub4[j * SU4];
        upB[j] = ub4[j * SU4 + 1];
    }

    for (int t0 = 0; t0 < TT; t0 += 4) {
        #pragma unroll
        for (int j = 0; j < 4; ++j) {
            const int t   = t0 + j;
            const int par = j & 1;        // parity (compile-time per j)
            const float  vnz = nzp[j];
            const float  vnx = nxp[j];
            const float4 ua  = upA[j];
            const float4 ubv = upB[j];

            // ---- phase 1: publish z_t broadcast (both waves, identical bits)
            smem[ZR_O + lane] = zl;
            smem[RZ_O + lane] = fmaxf(zl, 0.f);
            if (kh == 0) zob[lane + t * SNZ] = zl;   // emit z_t (pre-update)

            // u-dot (register operands, fills LDS latency shadow)
            float m0 = Crow[0] * ua.x,  m1 = Crow[1] * ua.y;
            float m2 = Crow[2] * ua.z,  m3 = Crow[3] * ua.w;
            m0 = fmaf(Crow[4], ubv.x, m0); m1 = fmaf(Crow[5], ubv.y, m1);
            m2 = fmaf(Crow[6], ubv.z, m2); m3 = fmaf(Crow[7], ubv.w, m3);

            // refill prefetch (clamped; tail values loaded but unused)
            {
                int tn = t + 4; tn = (tn < TT) ? tn : (TT - 1);
                nzp[j] = nzb[lane + tn * SNZ];
                nxp[j] = nxb[p + tn * SNX];
                upA[j] = ub4[tn * SU4];
                upB[j] = ub4[tn * SU4 + 1];
            }

            // W-half dot: 8 broadcast ds_read_b128 of relu(z_t)
            #pragma unroll
            for (int k4 = 0; k4 < 8; ++k4) {
                const float4 zz = *(const float4*)&smem[RZ_O + 32 * kh + 4 * k4];
                m0 = fmaf(Wrow[4 * k4 + 0], zz.x, m0);
                m1 = fmaf(Wrow[4 * k4 + 1], zz.y, m1);
                m2 = fmaf(Wrow[4 * k4 + 2], zz.z, m2);
                m3 = fmaf(Wrow[4 * k4 + 3], zz.w, m3);
            }

            // x-quarter dot: 4 broadcast ds_read_b128 of raw z_t
            float xa0 = 0.f, xa1 = 0.f;
            #pragma unroll
            for (int k4 = 0; k4 < 4; ++k4) {
                const float4 zz = *(const float4*)&smem[ZR_O + kq + 4 * k4];
                xa0 = fmaf(Brow[4 * k4 + 0], zz.x, xa0);
                xa1 = fmaf(Brow[4 * k4 + 1], zz.y, xa1);
                xa0 = fmaf(Brow[4 * k4 + 2], zz.z, xa0);
                xa1 = fmaf(Brow[4 * k4 + 3], zz.w, xa1);
            }
            float xpart = xa0 + xa1;
            xpart += __shfl_xor(xpart, 32);   // merge the two 16-k quarters

            const float mown = (m0 + m1) + (m2 + m3);
            smem[PM_O + par * 128 + kh * 64 + lane] = mown;
            if (kh == 0 && lane < 32) smem[PX_O + par * 32 + p] = xpart;

            lds_barrier();   // LDS-only drain + s_barrier (vmem stays in flight)

            // ---- phase 2: combine partials
            const float moth = smem[PM_O + par * 128 + (1 - kh) * 64 + lane];
            // kh-independent operand order -> both waves' z' are bit-identical
            const float h0 = (kh == 0) ? mown : moth;
            const float h1 = (kh == 0) ? moth : mown;

            if (kh == 1 && lane < 32) {      // wave1 finishes + stores x_t
                const float xoth = smem[PX_O + par * 32 + p];
                xob[p + t * SNX] = fmaf(vnx, rv, xpart + xoth);
            }

            // z_{t+1} = A_diag*z + (half0 + half1) + q*nz
            zl = fmaf(qv, vnz, fmaf(Ad, zl, h0 + h1));
        }
    }
}

extern "C" void kernel_launch(void* const* d_in, const int* in_sizes, int n_in,
                              void* d_out, int out_size, void* d_ws, size_t ws_size,
                              hipStream_t stream) {
    const float* u_  = (const float*)d_in[0];
    const float* z0_ = (const float*)d_in[1];
    const float* nz_ = (const float*)d_in[2];
    const float* nx_ = (const float*)d_in[3];
    const float* AW_ = (const float*)d_in[4];
    const float* C_  = (const float*)d_in[5];
    const float* B_  = (const float*)d_in[6];
    const float* Q_  = (const float*)d_in[7];
    const float* R_  = (const float*)d_in[8];

    float* zo = (float*)d_out;                 // (T,N,64) first
    float* xo = zo + (size_t)TT * NS * DZ;     // then (T,N,32)

    hipLaunchKernelGGL(plrnn_split_kernel, dim3(NS), dim3(128), 0, stream,
                       u_, z0_, nz_, nx_, AW_, C_, B_, Q_, R_, zo, xo);
}